// Round 2
// baseline (454.398 us; speedup 1.0000x reference)
//
#include <hip/hip_runtime.h>
#include <hip/hip_bf16.h>

#define B_ 16
#define S_ 8192
#define H_ 256
#define K_ 512           // 2H
#define NT_ 16           // n-tiles of 16 cols (H/16)

typedef __attribute__((ext_vector_type(8))) short bf16x8;
typedef __attribute__((ext_vector_type(4))) float f32x4;

static __device__ __forceinline__ unsigned short f2bf(float x) {
    __hip_bfloat16 h = __float2bfloat16(x);
    unsigned short r;
    __builtin_memcpy(&r, &h, 2);
    return r;
}

static __device__ __forceinline__ bf16x8 pack8(float4 f0, float4 f1) {
    bf16x8 r;
    r[0] = (short)f2bf(f0.x); r[1] = (short)f2bf(f0.y);
    r[2] = (short)f2bf(f0.z); r[3] = (short)f2bf(f0.w);
    r[4] = (short)f2bf(f1.x); r[5] = (short)f2bf(f1.y);
    r[6] = (short)f2bf(f1.z); r[7] = (short)f2bf(f1.w);
    return r;
}

static __device__ __forceinline__ float fast_tanh(float x) {
    x = fminf(15.f, fmaxf(-15.f, x));
    float e = __expf(2.f * x);
    return 1.f - 2.f * __builtin_amdgcn_rcpf(e + 1.f);
}

// ---------------------------------------------------------------------------
// Fused prep:
//  blocks 0..15  : repack W2[k][n]=attn_w[n][256+k] (bf16) into MFMA B-fragment
//                  order, [ks][nt][lane] so each ks-slice is 16KB contiguous.
//                  frag slot = (ks*16+nt)*64+lane holds B[k=ks*32+(lane>>4)*8+j]
//                  [n=nt*16+(lane&15)], j=0..7.
//  blocks 16..31 : q[b][h] = attn_b[h] + attn_w[h][0:256] . hidden[b]
//                  4 threads per h, float4 loads, shfl reduce.
// ---------------------------------------------------------------------------
__global__ __launch_bounds__(1024) void prep_kernel(const float* __restrict__ w,
                                                    const float* __restrict__ bias,
                                                    const float* __restrict__ hid,
                                                    bf16x8* __restrict__ wfrag,
                                                    float* __restrict__ q) {
    int blk = blockIdx.x;
    int tid = threadIdx.x;
    if (blk < 16) {
        int slot = blk * 1024 + tid;        // 0..16383
        int lane = slot & 63;
        int nt   = (slot >> 6) & 15;
        int ks   = slot >> 10;
        int n  = (nt << 4) + (lane & 15);
        int k0 = (ks << 5) + ((lane >> 4) << 3);
        const float* src = w + n * 768 + 256 + k0;
        float4 f0 = *(const float4*)(src);
        float4 f1 = *(const float4*)(src + 4);
        wfrag[slot] = pack8(f0, f1);
    } else {
        int b = blk - 16;
        int h = tid >> 2, part = tid & 3;
        const float* wr = w + h * 768 + part * 64;
        const float* hb = hid + b * H_ + part * 64;
        float acc = 0.f;
#pragma unroll
        for (int i = 0; i < 16; ++i) {
            float4 a = *(const float4*)(wr + i * 4);
            float4 x = *(const float4*)(hb + i * 4);
            acc += a.x * x.x + a.y * x.y + a.z * x.z + a.w * x.w;
        }
        acc += __shfl_xor(acc, 1);
        acc += __shfl_xor(acc, 2);
        if (part == 0) q[b * H_ + h] = acc + bias[h];
    }
}

// ---------------------------------------------------------------------------
// Energy: one block = 64 rows of one batch; each wave owns 16 rows x all 256
// cols. A-fragments straight from global (own rows, zero duplication, no LDS,
// no barriers); B-fragments from L1/L2-resident wfrag. Fused tanh + v-dot +
// in-wave shfl reduction, direct store.
// ---------------------------------------------------------------------------
__global__ __launch_bounds__(256) void energy_kernel(const float* __restrict__ enc,
                                                     const bf16x8* __restrict__ wfrag,
                                                     const float* __restrict__ qv,
                                                     const float* __restrict__ vv,
                                                     float* __restrict__ ener) {
    const int bid  = blockIdx.x;
    const int b    = bid >> 7;              // / 128
    const int s0   = (bid & 127) * 64;
    const int tid  = threadIdx.x;
    const int lane = tid & 63;
    const int wv   = tid >> 6;
    const int lr   = lane & 15;
    const int lg   = lane >> 4;
    const int r0   = s0 + wv * 16;

    // lane's A row pointer: row r0+lr, k-offset lg*8
    const float* arow = enc + ((size_t)(b * S_ + r0 + lr)) * K_ + lg * 8;
    const bf16x8* wbase = wfrag + lane;

    f32x4 acc[NT_];
#pragma unroll
    for (int nt = 0; nt < NT_; ++nt) acc[nt] = (f32x4){0.f, 0.f, 0.f, 0.f};

#pragma unroll 2
    for (int ks = 0; ks < 16; ++ks) {
        float4 f0 = *(const float4*)(arow + ks * 32);
        float4 f1 = *(const float4*)(arow + ks * 32 + 4);
        bf16x8 a = pack8(f0, f1);
#pragma unroll
        for (int nt = 0; nt < NT_; ++nt) {
            bf16x8 bf = wbase[(ks * 16 + nt) * 64];
            acc[nt] = __builtin_amdgcn_mfma_f32_16x16x32_bf16(a, bf, acc[nt], 0, 0, 0);
        }
    }

    // ---- epilogue: e[row] = sum_h v[h] * tanh(q[h] + acc) ----
    const float* qb = qv + b * H_;
    float e[4] = {0.f, 0.f, 0.f, 0.f};
#pragma unroll
    for (int nt = 0; nt < NT_; ++nt) {
        float qn = qb[nt * 16 + lr];
        float vn = vv[nt * 16 + lr];
#pragma unroll
        for (int j = 0; j < 4; ++j)
            e[j] += vn * fast_tanh(qn + acc[nt][j]);
    }
#pragma unroll
    for (int j = 0; j < 4; ++j) {
        e[j] += __shfl_xor(e[j], 1);
        e[j] += __shfl_xor(e[j], 2);
        e[j] += __shfl_xor(e[j], 4);
        e[j] += __shfl_xor(e[j], 8);
    }
    if (lr == 0) {
        float* op = ener + b * S_ + r0 + lg * 4;
        op[0] = e[0]; op[1] = e[1]; op[2] = e[2]; op[3] = e[3];
    }
}

// ---------------------------------------------------------------------------
// Softmax over S per batch
// ---------------------------------------------------------------------------
__global__ __launch_bounds__(1024) void softmax_kernel(const float* __restrict__ ener,
                                                       float* __restrict__ out) {
    __shared__ float redm[16], reds[16];
    int b = blockIdx.x, tid = threadIdx.x;
    int lane = tid & 63, wv = tid >> 6;
    const float* e = ener + b * S_;
    float v[8];
#pragma unroll
    for (int i = 0; i < 8; ++i) v[i] = e[i * 1024 + tid];
    float m = v[0];
#pragma unroll
    for (int i = 1; i < 8; ++i) m = fmaxf(m, v[i]);
#pragma unroll
    for (int msk = 1; msk < 64; msk <<= 1) m = fmaxf(m, __shfl_xor(m, msk));
    if (lane == 0) redm[wv] = m;
    __syncthreads();
    float M = redm[0];
#pragma unroll
    for (int i = 1; i < 16; ++i) M = fmaxf(M, redm[i]);
    float s = 0.f;
#pragma unroll
    for (int i = 0; i < 8; ++i) { v[i] = __expf(v[i] - M); s += v[i]; }
#pragma unroll
    for (int msk = 1; msk < 64; msk <<= 1) s += __shfl_xor(s, msk);
    if (lane == 0) reds[wv] = s;
    __syncthreads();
    float T = 0.f;
#pragma unroll
    for (int i = 0; i < 16; ++i) T += reds[i];
    float inv = 1.0f / T;
    float* ob = out + b * S_;
#pragma unroll
    for (int i = 0; i < 8; ++i) ob[i * 1024 + tid] = v[i] * inv;
}

extern "C" void kernel_launch(void* const* d_in, const int* in_sizes, int n_in,
                              void* d_out, int out_size, void* d_ws, size_t ws_size,
                              hipStream_t stream) {
    const float* hidden = (const float*)d_in[0];
    const float* enc    = (const float*)d_in[1];
    const float* attn_w = (const float*)d_in[2];
    const float* attn_b = (const float*)d_in[3];
    const float* v      = (const float*)d_in[4];
    float* out = (float*)d_out;

    char* ws = (char*)d_ws;
    bf16x8* wfrag = (bf16x8*)ws;                          // 256 KB
    float*  q     = (float*)(ws + 262144);                // 16 KB
    float*  ener  = (float*)(ws + 262144 + 16384);        // 512 KB

    prep_kernel<<<32, 1024, 0, stream>>>(attn_w, attn_b, hidden, wfrag, q);
    energy_kernel<<<B_ * (S_ / 64), 256, 0, stream>>>(enc, wfrag, q, v, ener);
    softmax_kernel<<<B_, 1024, 0, stream>>>(ener, out);
}

// Round 3
// 409.534 us; speedup vs baseline: 1.1095x; 1.1095x over previous
//
#include <hip/hip_runtime.h>
#include <hip/hip_bf16.h>

#define B_ 16
#define S_ 8192
#define H_ 256
#define K_ 512           // 2H
#define NT32_ 8          // 256 cols / 32
#define NKS_ 32          // K / 16

typedef __attribute__((ext_vector_type(8)))  short bf16x8;
typedef __attribute__((ext_vector_type(16))) float f32x16;
typedef unsigned int u32;

static __device__ __forceinline__ unsigned short f2bf(float x) {
    __hip_bfloat16 h = __float2bfloat16(x);
    unsigned short r;
    __builtin_memcpy(&r, &h, 2);
    return r;
}

static __device__ __forceinline__ bf16x8 pack8(float4 f0, float4 f1) {
    bf16x8 r;
    r[0] = (short)f2bf(f0.x); r[1] = (short)f2bf(f0.y);
    r[2] = (short)f2bf(f0.z); r[3] = (short)f2bf(f0.w);
    r[4] = (short)f2bf(f1.x); r[5] = (short)f2bf(f1.y);
    r[6] = (short)f2bf(f1.z); r[7] = (short)f2bf(f1.w);
    return r;
}

static __device__ __forceinline__ float fast_tanh(float x) {
    x = fminf(15.f, fmaxf(-15.f, x));
    float e = __expf(2.f * x);
    return 1.f - 2.f * __builtin_amdgcn_rcpf(e + 1.f);
}

static __device__ __forceinline__ void gload_lds16(const void* g, void* l) {
    __builtin_amdgcn_global_load_lds((const __attribute__((address_space(1))) u32*)g,
                                     (__attribute__((address_space(3))) u32*)l, 16, 0, 0);
}

// ---------------------------------------------------------------------------
// Fused prep:
//  blocks 0..15  : repack W2[k][n]=attn_w[n][256+k] (bf16) into 32x32x16 MFMA
//                  B-fragment order: slot = (ks*8+nt)*64+lane holds 8 bf16 of
//                  B[k = ks*16+(lane>>5)*8+j][n = nt*32+(lane&31)], j=0..7.
//  blocks 16..31 : q[b][h] = attn_b[h] + attn_w[h][0:256] . hidden[b]
// ---------------------------------------------------------------------------
__global__ __launch_bounds__(1024) void prep_kernel(const float* __restrict__ w,
                                                    const float* __restrict__ bias,
                                                    const float* __restrict__ hid,
                                                    bf16x8* __restrict__ wfrag,
                                                    float* __restrict__ q) {
    int blk = blockIdx.x;
    int tid = threadIdx.x;
    if (blk < 16) {
        int slot = blk * 1024 + tid;        // 0..16383
        int lane = slot & 63;
        int nt   = (slot >> 6) & 7;
        int ks   = slot >> 9;
        int n  = (nt << 5) + (lane & 31);
        int k0 = (ks << 4) + ((lane >> 5) << 3);
        const float* src = w + n * 768 + 256 + k0;
        float4 f0 = *(const float4*)(src);
        float4 f1 = *(const float4*)(src + 4);
        wfrag[slot] = pack8(f0, f1);
    } else {
        int b = blk - 16;
        int h = tid >> 2, part = tid & 3;
        const float* wr = w + h * 768 + part * 64;
        const float* hb = hid + b * H_ + part * 64;
        float acc = 0.f;
#pragma unroll
        for (int i = 0; i < 16; ++i) {
            float4 a = *(const float4*)(wr + i * 4);
            float4 x = *(const float4*)(hb + i * 4);
            acc += a.x * x.x + a.y * x.y + a.z * x.z + a.w * x.w;
        }
        acc += __shfl_xor(acc, 1);
        acc += __shfl_xor(acc, 2);
        if (part == 0) q[b * H_ + h] = acc + bias[h];
    }
}

// ---------------------------------------------------------------------------
// Energy v3: block = 128 rows x 256 cols, 4 waves, each wave one 32x32x16
// m-tile row-band (32 rows) x all 256 cols. B staged through double-buffered
// LDS in 32KB chunks (4 ks-slices) via global_load_lds; A streamed from
// global with a depth-4 prefetch ring; fused tanh + v-dot epilogue.
// ---------------------------------------------------------------------------
__global__ __launch_bounds__(256) void energy_kernel(const float* __restrict__ enc,
                                                     const char* __restrict__ wfrag,
                                                     const float* __restrict__ qv,
                                                     const float* __restrict__ vv,
                                                     float* __restrict__ ener) {
    __shared__ char Bs[2][32768];           // 64 KB double-buffered B chunks

    const int bid  = blockIdx.x;
    const int b    = bid >> 6;              // 64 s-tiles per batch
    const int s0   = (bid & 63) * 128;
    const int tid  = threadIdx.x;
    const int lane = tid & 63;
    const int wv   = tid >> 6;
    const int lc   = lane & 31;             // col-within-tile / row-within-mtile
    const int hi   = lane >> 5;
    const int r0   = s0 + wv * 32;

    // A row pointer: row r0+lc, k-offset hi*8 (floats)
    const float* arow = enc + ((size_t)(b * S_ + r0 + lc)) * K_ + hi * 8;

    // ---- stage chunks 0 and 1 (32 KB each) ----
#pragma unroll
    for (int i = 0; i < 8; ++i) {
        int off = i * 4096 + tid * 16;
        gload_lds16(wfrag + off,         Bs[0] + off);
        gload_lds16(wfrag + 32768 + off, Bs[1] + off);
    }

    // ---- A prefetch prologue: ks = 0..3 ----
    float4 fbuf[4][2];
#pragma unroll
    for (int p = 0; p < 4; ++p) {
        fbuf[p][0] = *(const float4*)(arow + p * 16);
        fbuf[p][1] = *(const float4*)(arow + p * 16 + 4);
    }

    f32x16 acc[NT32_];
#pragma unroll
    for (int nt = 0; nt < NT32_; ++nt)
#pragma unroll
        for (int r = 0; r < 16; ++r) acc[nt][r] = 0.f;

    __syncthreads();                        // drains both stages + A prologue

#pragma unroll
    for (int c = 0; c < 8; ++c) {
        const char* Bb = Bs[c & 1];
#pragma unroll
        for (int ksl = 0; ksl < 4; ++ksl) {
            const int ks = c * 4 + ksl;
            bf16x8 a = pack8(fbuf[ks & 3][0], fbuf[ks & 3][1]);
            if (ks + 4 < NKS_) {            // refill ring slot
                fbuf[ks & 3][0] = *(const float4*)(arow + (ks + 4) * 16);
                fbuf[ks & 3][1] = *(const float4*)(arow + (ks + 4) * 16 + 4);
            }
#pragma unroll
            for (int nt = 0; nt < NT32_; ++nt) {
                bf16x8 bfr = *(const bf16x8*)(Bb + ksl * 8192 + nt * 1024 + lane * 16);
                acc[nt] = __builtin_amdgcn_mfma_f32_32x32x16_bf16(a, bfr, acc[nt], 0, 0, 0);
            }
        }
        __syncthreads();                    // all waves done with Bs[c&1]
        if (c < 6) {                        // stage chunk c+2 into the freed buffer
            const char* src = wfrag + (c + 2) * 32768;
#pragma unroll
            for (int i = 0; i < 8; ++i) {
                int off = i * 4096 + tid * 16;
                gload_lds16(src + off, Bs[c & 1] + off);
            }
        }
    }

    // ---- epilogue: e[row] = sum_h v[h] * tanh(q[h] + acc) ----
    const float* qb = qv + b * H_;
    float er[16];
#pragma unroll
    for (int r = 0; r < 16; ++r) er[r] = 0.f;
#pragma unroll
    for (int nt = 0; nt < NT32_; ++nt) {
        float qn = qb[nt * 32 + lc];
        float vn = vv[nt * 32 + lc];
#pragma unroll
        for (int r = 0; r < 16; ++r)
            er[r] += vn * fast_tanh(qn + acc[nt][r]);
    }
#pragma unroll
    for (int r = 0; r < 16; ++r) {
        er[r] += __shfl_xor(er[r], 1);
        er[r] += __shfl_xor(er[r], 2);
        er[r] += __shfl_xor(er[r], 4);
        er[r] += __shfl_xor(er[r], 8);
        er[r] += __shfl_xor(er[r], 16);
    }
    if (lc == 0) {
        float* op = ener + b * S_ + r0;
#pragma unroll
        for (int r = 0; r < 16; ++r)
            op[(r & 3) + 8 * (r >> 2) + 4 * hi] = er[r];
    }
}

// ---------------------------------------------------------------------------
// Softmax over S per batch
// ---------------------------------------------------------------------------
__global__ __launch_bounds__(1024) void softmax_kernel(const float* __restrict__ ener,
                                                       float* __restrict__ out) {
    __shared__ float redm[16], reds[16];
    int b = blockIdx.x, tid = threadIdx.x;
    int lane = tid & 63, wv = tid >> 6;
    const float* e = ener + b * S_;
    float v[8];
#pragma unroll
    for (int i = 0; i < 8; ++i) v[i] = e[i * 1024 + tid];
    float m = v[0];
#pragma unroll
    for (int i = 1; i < 8; ++i) m = fmaxf(m, v[i]);
#pragma unroll
    for (int msk = 1; msk < 64; msk <<= 1) m = fmaxf(m, __shfl_xor(m, msk));
    if (lane == 0) redm[wv] = m;
    __syncthreads();
    float M = redm[0];
#pragma unroll
    for (int i = 1; i < 16; ++i) M = fmaxf(M, redm[i]);
    float s = 0.f;
#pragma unroll
    for (int i = 0; i < 8; ++i) { v[i] = __expf(v[i] - M); s += v[i]; }
#pragma unroll
    for (int msk = 1; msk < 64; msk <<= 1) s += __shfl_xor(s, msk);
    if (lane == 0) reds[wv] = s;
    __syncthreads();
    float T = 0.f;
#pragma unroll
    for (int i = 0; i < 16; ++i) T += reds[i];
    float inv = 1.0f / T;
    float* ob = out + b * S_;
#pragma unroll
    for (int i = 0; i < 8; ++i) ob[i * 1024 + tid] = v[i] * inv;
}

extern "C" void kernel_launch(void* const* d_in, const int* in_sizes, int n_in,
                              void* d_out, int out_size, void* d_ws, size_t ws_size,
                              hipStream_t stream) {
    const float* hidden = (const float*)d_in[0];
    const float* enc    = (const float*)d_in[1];
    const float* attn_w = (const float*)d_in[2];
    const float* attn_b = (const float*)d_in[3];
    const float* v      = (const float*)d_in[4];
    float* out = (float*)d_out;

    char* ws = (char*)d_ws;
    bf16x8* wfrag = (bf16x8*)ws;                          // 256 KB
    float*  q     = (float*)(ws + 262144);                // 16 KB
    float*  ener  = (float*)(ws + 262144 + 16384);        // 512 KB

    prep_kernel<<<32, 1024, 0, stream>>>(attn_w, attn_b, hidden, wfrag, q);
    energy_kernel<<<B_ * (S_ / 128), 256, 0, stream>>>(enc, (const char*)wfrag, q, v, ener);
    softmax_kernel<<<B_, 1024, 0, stream>>>(ener, out);
}